// Round 16
// baseline (53.608 us; speedup 1.0000x reference)
//
#include <hip/hip_runtime.h>
#include <math.h>

#define B 4
#define T 2048
#define D 1024
#define S 64
#define NC 32      // chunks per batch
#define CH 64      // chunk length

typedef float f32x4 __attribute__((ext_vector_type(4)));
typedef short bf16x8 __attribute__((ext_vector_type(8)));

__device__ inline ushort f2b(float f) {   // fp32 -> bf16 RNE
  unsigned u = __float_as_uint(f);
  u += 0x7fff + ((u >> 16) & 1);
  return (ushort)(u >> 16);
}
__device__ inline float b2f(ushort h) { return __uint_as_float(((unsigned)h) << 16); }

// ---------------- bf16-MFMA projection, BM=32 BN=128 BK=128, grid 512 (2 blocks/CU)
// XCD-paired: (mt,cb=0)/(mt,cb=1) share the x tile via one XCD's L2.
// B operand staged DIRECTLY from fp32 weights with inline f2b (k_prep eliminated);
// LDS image identical to the old Wt path: lds[row*128+q*8+j] = W(row)[kc+((q^(row&7))<<3)+j].
__global__ __launch_bounds__(256) void k_proj(const float* __restrict__ x,
                                              const float* __restrict__ Wk,
                                              const float* __restrict__ Wq,
                                              const float* __restrict__ Wv,
                                              const float* __restrict__ Wg,
                                              const float* __restrict__ cosT,
                                              const float* __restrict__ sinT,
                                              const float* __restrict__ bgp,
                                              ushort* __restrict__ qrb,
                                              ushort* __restrict__ krb,
                                              ushort* __restrict__ avb,
                                              float* __restrict__ knw,
                                              float* __restrict__ alw) {
  __shared__ ushort lA[2][32 * 128];    // 8KB x2
  __shared__ ushort lB[2][128 * 128];   // 32KB x2   (total 80KB -> 2 blocks/CU)
  int tid = threadIdx.x;
  int bid = blockIdx.x;
  int mt = (bid >> 4) * 8 + (bid & 7), cb = (bid >> 3) & 1;
  int row0 = mt * 32;
  int wv = tid >> 6, l = tid & 63, lr = l >> 4, lc = l & 15;
  int arow = tid >> 4, ac16 = tid & 15;
  int asw = (ac16 ^ (arow & 7)) << 3;
  const float* xr0 = &x[(size_t)(row0 + arow) * D + asw];
  const float* xr1 = &x[(size_t)(row0 + arow + 16) * D + asw];   // (arow+16)&7 == arow&7
  int f0 = ((wv >> 1) << 2) | (wv & 1);   // wave's first n-frag; RoPE pair is f0+2

  // per-thread B-staging source: row = tid>>1 (0..127), this thread covers chunks h*8..h*8+7
  int brow = tid >> 1, bh = (tid & 1) * 8;
  const float* bsrc = nullptr;
  if (cb == 0) bsrc = (brow < 64) ? &Wk[(size_t)brow * D] : &Wq[(size_t)(brow - 64) * D];
  else if (brow < 64) bsrc = &Wv[(size_t)brow * D];
  else if (brow == 64) bsrc = Wg;       // col 192 = gate; rows 65..127 stay zero
  int brs = brow & 7;

  f32x4 acc[2][2];
#pragma unroll
  for (int mi = 0; mi < 2; ++mi)
#pragma unroll
    for (int ni = 0; ni < 2; ++ni) acc[mi][ni] = (f32x4){0.f, 0.f, 0.f, 0.f};

  float af0[8], af1[8];
  // ---- prologue: tile 0 -> buf 0
  {
    *(float4*)&af0[0] = *(const float4*)&xr0[0];
    *(float4*)&af0[4] = *(const float4*)&xr0[4];
    *(float4*)&af1[0] = *(const float4*)&xr1[0];
    *(float4*)&af1[4] = *(const float4*)&xr1[4];
    ushort* drow = &lB[0][brow * 128];
#pragma unroll
    for (int qi = 0; qi < 8; ++qi) {
      int q = bh + qi;
      union { ushort us[8]; uint4 v; } u;
      if (bsrc) {
        const float* p = &bsrc[(q ^ brs) << 3];
        float4 a = *(const float4*)p;
        float4 b2 = *(const float4*)(p + 4);
        u.us[0] = f2b(a.x); u.us[1] = f2b(a.y); u.us[2] = f2b(a.z); u.us[3] = f2b(a.w);
        u.us[4] = f2b(b2.x); u.us[5] = f2b(b2.y); u.us[6] = f2b(b2.z); u.us[7] = f2b(b2.w);
      } else {
#pragma unroll
        for (int j = 0; j < 8; ++j) u.us[j] = 0;
      }
      *(uint4*)&drow[q * 8] = u.v;
    }
    union { ushort h[8]; uint4 v; } u0, u1;
#pragma unroll
    for (int j = 0; j < 8; ++j) { u0.h[j] = f2b(af0[j]); u1.h[j] = f2b(af1[j]); }
    *(uint4*)&lA[0][arow * 128 + ac16 * 8] = u0.v;
    *(uint4*)&lA[0][(arow + 16) * 128 + ac16 * 8] = u1.v;
  }
  __syncthreads();

  const int NT = D / 128;
  for (int t = 0; t < NT; ++t) {
    int p = t & 1;
    if (t + 1 < NT) {                     // issue next-tile A loads early
      int kc = (t + 1) * 128;
      *(float4*)&af0[0] = *(const float4*)&xr0[kc];
      *(float4*)&af0[4] = *(const float4*)&xr0[kc + 4];
      *(float4*)&af1[0] = *(const float4*)&xr1[kc];
      *(float4*)&af1[4] = *(const float4*)&xr1[kc + 4];
    }
    bf16x8 afr[2][4], bfr[2][4];
#pragma unroll
    for (int mi = 0; mi < 2; ++mi)
#pragma unroll
      for (int ks = 0; ks < 4; ++ks)
        afr[mi][ks] = *(const bf16x8*)&lA[p][(mi * 16 + lc) * 128 + (((ks * 4 + lr) ^ (lc & 7)) << 3)];
#pragma unroll
    for (int ni = 0; ni < 2; ++ni)
#pragma unroll
      for (int ks = 0; ks < 4; ++ks)
        bfr[ni][ks] = *(const bf16x8*)&lB[p][((f0 + 2 * ni) * 16 + lc) * 128 + (((ks * 4 + lr) ^ (lc & 7)) << 3)];
#pragma unroll
    for (int ks = 0; ks < 4; ++ks)
#pragma unroll
      for (int mi = 0; mi < 2; ++mi)
#pragma unroll
        for (int ni = 0; ni < 2; ++ni)
          acc[mi][ni] = __builtin_amdgcn_mfma_f32_16x16x32_bf16(afr[mi][ks], bfr[ni][ks], acc[mi][ni], 0, 0, 0);
    if (t + 1 < NT) {
      int kc = (t + 1) * 128;
      // stage B tile t+1 from fp32 (loads hoisted above MFMAs by the scheduler)
      ushort* drow = &lB[p ^ 1][brow * 128];
#pragma unroll
      for (int qi = 0; qi < 8; ++qi) {
        int q = bh + qi;
        union { ushort us[8]; uint4 v; } u;
        if (bsrc) {
          const float* pp = &bsrc[kc + ((q ^ brs) << 3)];
          float4 a = *(const float4*)pp;
          float4 b2 = *(const float4*)(pp + 4);
          u.us[0] = f2b(a.x); u.us[1] = f2b(a.y); u.us[2] = f2b(a.z); u.us[3] = f2b(a.w);
          u.us[4] = f2b(b2.x); u.us[5] = f2b(b2.y); u.us[6] = f2b(b2.z); u.us[7] = f2b(b2.w);
        } else {
#pragma unroll
          for (int j = 0; j < 8; ++j) u.us[j] = 0;
        }
        *(uint4*)&drow[q * 8] = u.v;
      }
      union { ushort h[8]; uint4 v; } u0, u1;
#pragma unroll
      for (int j = 0; j < 8; ++j) { u0.h[j] = f2b(af0[j]); u1.h[j] = f2b(af1[j]); }
      *(uint4*)&lA[p ^ 1][arow * 128 + ac16 * 8] = u0.v;
      *(uint4*)&lA[p ^ 1][(arow + 16) * 128 + ac16 * 8] = u1.v;
    }
    __syncthreads();
  }

  // epilogue. C/D map: row = mi*16+lr*4+r, col(frag f) = f*16+lc.
  float (*s_red)[32] = (float (*)[32])(&lA[0][0]);   // alias dead lA (keeps LDS at 80KB)
  float bgv = bgp[0];
  int c0 = (wv & 1) * 16 + lc;   // col within the 64-wide group; partner c0+32
  if (cb == 0) {
    ushort* dst = (wv < 2) ? krb : qrb;
#pragma unroll
    for (int mi = 0; mi < 2; ++mi)
#pragma unroll
      for (int r = 0; r < 4; ++r) {
        int lrow = mi * 16 + lr * 4 + r;
        int grow = row0 + lrow;
        int tt = grow & (T - 1);
        float a0 = acc[mi][0][r], a1 = acc[mi][1][r];
        float cv0 = cosT[tt * S + c0], sv0 = sinT[tt * S + c0];
        float cv1 = cosT[tt * S + c0 + 32], sv1 = sinT[tt * S + c0 + 32];
        float o0 = a0 * cv0 - a1 * sv0;
        float o1 = a1 * cv1 + a0 * sv1;
        dst[(size_t)grow * S + c0] = f2b(o0);
        dst[(size_t)grow * S + c0 + 32] = f2b(o1);
        if (wv < 2) {
          float nrm = o0 * o0 + o1 * o1;
#pragma unroll
          for (int off = 1; off < 16; off <<= 1) nrm += __shfl_xor(nrm, off, 64);
          if (lc == 0) s_red[wv][lrow] = nrm;
        }
      }
    __syncthreads();
    if (tid < 32) knw[row0 + tid] = s_red[0][tid] + s_red[1][tid];
  } else {
    if (wv == 2 && lc == 0) {    // gate = local col 64 = frag 4, lc==0
#pragma unroll
      for (int mi = 0; mi < 2; ++mi)
#pragma unroll
        for (int r = 0; r < 4; ++r) {
          int lrow = mi * 16 + lr * 4 + r;
          s_red[0][lrow] = 1.f / (1.f + __expf(-(acc[mi][0][r] + bgv)));
        }
    }
    __syncthreads();
    if (wv < 2) {
#pragma unroll
      for (int mi = 0; mi < 2; ++mi)
#pragma unroll
        for (int r = 0; r < 4; ++r) {
          int lrow = mi * 16 + lr * 4 + r, grow = row0 + lrow;
          float al = s_red[0][lrow];
          avb[(size_t)grow * S + c0] = f2b(al * acc[mi][0][r]);
          avb[(size_t)grow * S + c0 + 32] = f2b(al * acc[mi][1][r]);
        }
    }
    if (tid < 32) alw[row0 + tid] = s_red[0][tid];
  }
}

// ---------------- per-chunk: gate+cumsum + outer-product Mc + avT; 2 blocks/chunk (XCD-paired)
// Also folds the Wout->bf16 conversion (one elem per thread; k_ao consumes Wo after this kernel).
__global__ __launch_bounds__(256) void k_chunk(const ushort* __restrict__ krb,
                                               const ushort* __restrict__ avb,
                                               const float* __restrict__ knw,
                                               const float* __restrict__ alw,
                                               const float* __restrict__ Wout,
                                               ushort* __restrict__ Wo,
                                               float* __restrict__ lcum,
                                               float* __restrict__ csum,
                                               float* __restrict__ Mc,
                                               ushort* __restrict__ avT) {
  int bid = blockIdx.x;
  int tid = threadIdx.x;
  {
    int j = bid * 256 + tid;               // 256 blocks x 256 thr = 65536 = D*S
    Wo[j] = f2b(Wout[j]);
  }
  int cid = (bid >> 4) * 8 + (bid & 7), half = (bid >> 3) & 1;
  int b = cid >> 5, ch = cid & 31;
  int rbase = b * T + ch * CH;
  __shared__ float lc[CH], wts[CH];
  __shared__ float krs[CH][68], avs[CH][68];

  if (tid < 64) {
    float al = alw[rbase + tid], kn = knw[rbase + tid];
    float gate = al * kn * 0.1f;
    float sp = (gate > 20.f) ? gate : log1pf(expf(gate));
    float g = expf(-sp);
    float v = logf(g + 1e-8f);
#pragma unroll
    for (int off = 1; off < 64; off <<= 1) {
      float n = __shfl_up(v, off, 64);
      if (tid >= off) v += n;
    }
    lc[tid] = v;
    if (half == 0) lcum[rbase + tid] = v;
  }
  for (int i = tid; i < 512; i += 256) {
    int t = i >> 3, c8 = i & 7;
    uint4 kv = *(const uint4*)&krb[(size_t)(rbase + t) * S + c8 * 8];
    uint4 a4 = *(const uint4*)&avb[(size_t)(rbase + t) * S + c8 * 8];
    const ushort* kh = (const ushort*)&kv;
    const ushort* ah = (const ushort*)&a4;
    float kf[8], af_[8];
#pragma unroll
    for (int j = 0; j < 8; ++j) { kf[j] = b2f(kh[j]); af_[j] = b2f(ah[j]); }
    *(float4*)&krs[t][c8 * 8]     = *(const float4*)&kf[0];
    *(float4*)&krs[t][c8 * 8 + 4] = *(const float4*)&kf[4];
    *(float4*)&avs[t][c8 * 8]     = *(const float4*)&af_[0];
    *(float4*)&avs[t][c8 * 8 + 4] = *(const float4*)&af_[4];
  }
  __syncthreads();
  float tot = lc[63];
  if (tid < 64) wts[tid] = __expf(tot - lc[tid]);   // exponent <= 0
  if (tid == 63 && half == 0) csum[b * NC + ch] = tot;
  __syncthreads();
  for (int i = tid; i < 2048; i += 256) {           // this half's v-range transpose
    int v = half * 32 + (i >> 6), t = i & 63;
    avT[(size_t)(b * NC + ch) * 4096 + v * 64 + t] = f2b(avs[t][v]);
  }
  int k = tid & 63, vg = tid >> 6;
  int v0 = half * 32 + vg * 8;
  float acc[8];
#pragma unroll
  for (int j = 0; j < 8; ++j) acc[j] = 0.f;
  for (int t = 0; t < CH; ++t) {
    float kw = krs[t][k] * wts[t];
    float4 a0 = *(const float4*)&avs[t][v0];
    float4 a1 = *(const float4*)&avs[t][v0 + 4];
    acc[0] += kw * a0.x; acc[1] += kw * a0.y; acc[2] += kw * a0.z; acc[3] += kw * a0.w;
    acc[4] += kw * a1.x; acc[5] += kw * a1.y; acc[6] += kw * a1.z; acc[7] += kw * a1.w;
  }
  size_t ob = (size_t)(b * NC + ch) * 4096;
#pragma unroll
  for (int j = 0; j < 8; ++j) Mc[ob + (v0 + j) * 64 + k] = acc[j];
}

// ---------------- chunk-level scan: preloaded Mc; 256 blocks x 64 threads
__global__ __launch_bounds__(64) void k_scan(const float* __restrict__ state,
                                             const float* __restrict__ csum,
                                             const float* __restrict__ Mc,
                                             ushort* __restrict__ Scb,
                                             float* __restrict__ newstate) {
  int gid = blockIdx.x * 64 + threadIdx.x;   // B*S*S = 16384
  int b = gid >> 12, e = gid & 4095;
  __shared__ float eg[NC];
  if (threadIdx.x < NC) eg[threadIdx.x] = __expf(csum[b * NC + threadIdx.x]);
  float m[NC];
#pragma unroll
  for (int c = 0; c < NC; ++c) m[c] = Mc[(size_t)(b * NC + c) * 4096 + e];
  float s = state[gid];
  __syncthreads();
#pragma unroll
  for (int c = 0; c < NC; ++c) {
    Scb[(size_t)(b * NC + c) * 4096 + e] = f2b(s);
    s = s * eg[c] + m[c];
  }
  newstate[gid] = s;
}

// ---------------- fused intra-chunk attention + output GEMM, 512 threads (8 waves)
// Wave-specialized attn: waves 0-3 do GEMM1 (QK^T) + P-decay, CONCURRENTLY waves 4-7
// do GEMM2 (q.Sc^T) + esh; after one barrier waves 4-7 do GEMM3 + ret write.
__global__ __launch_bounds__(512) void k_ao(const ushort* __restrict__ qrb,
                                            const ushort* __restrict__ krb,
                                            const ushort* __restrict__ avT,
                                            const ushort* __restrict__ Scb,
                                            const float* __restrict__ lcum,
                                            const ushort* __restrict__ Wo,
                                            const float* __restrict__ bout,
                                            float* __restrict__ out) {
  int bid = blockIdx.x;
  int cid = (bid >> 4) * 8 + (bid & 7), nh = (bid >> 3) & 1;
  int b = cid >> 5, ch = cid & 31;
  int rbase = b * T + ch * CH;
  size_t cb2 = (size_t)(b * NC + ch) * 4096;
  __shared__ ushort qs[64 * 64], ks_[64 * 64], vs[64 * 64], ss[64 * 64], ps[64 * 64];
  __shared__ float lcv[CH];
  int tid = threadIdx.x;
  int wv = tid >> 6, l = tid & 63, lr = l >> 4, lc = l & 15;
  int colw = nh * 512 + wv * 32;

  // issue ALL Wout frags at entry (latency hides under staging + attn)
  bf16x8 bw[2][4];
#pragma unroll
  for (int g = 0; g < 2; ++g)
#pragma unroll
    for (int ni = 0; ni < 2; ++ni)
#pragma unroll
      for (int ks = 0; ks < 2; ++ks)
        bw[g][ni * 2 + ks] = *(const bf16x8*)&Wo[(size_t)(colw + g * 256 + ni * 16 + lc) * 64 + (ks * 4 + lr) * 8];

  if (tid < 64) lcv[tid] = lcum[rbase + tid];
  {
    int row = tid >> 3, c8 = tid & 7;      // 512 threads = 512 chunk-slots
    int sc = (c8 ^ (row & 7)) << 3;
    *(uint4*)&qs[row * 64 + c8 * 8]  = *(const uint4*)&qrb[(size_t)(rbase + row) * S + sc];
    *(uint4*)&ks_[row * 64 + c8 * 8] = *(const uint4*)&krb[(size_t)(rbase + row) * S + sc];
    *(uint4*)&vs[row * 64 + c8 * 8]  = *(const uint4*)&avT[cb2 + row * 64 + sc];
    *(uint4*)&ss[row * 64 + c8 * 8]  = *(const uint4*)&Scb[cb2 + row * 64 + sc];
  }
  __syncthreads();

  int tq = (wv & 3) * 16;
  bf16x8 qa[2];
#pragma unroll
  for (int ks = 0; ks < 2; ++ks)
    qa[ks] = *(const bf16x8*)&qs[(tq + lc) * 64 + (((ks * 4 + lr) ^ (lc & 7)) << 3)];

  f32x4 a2[4];
#pragma unroll
  for (int ni = 0; ni < 4; ++ni) a2[ni] = (f32x4){0, 0, 0, 0};

  if (wv < 4) {
    // GEMM1: QK^T -> P with causal decay -> ps (swizzled)
    f32x4 a1[4];
#pragma unroll
    for (int ni = 0; ni < 4; ++ni) a1[ni] = (f32x4){0, 0, 0, 0};
#pragma unroll
    for (int ni = 0; ni < 4; ++ni)
#pragma unroll
      for (int ks = 0; ks < 2; ++ks) {
        bf16x8 kf = *(const bf16x8*)&ks_[(ni * 16 + lc) * 64 + (((ks * 4 + lr) ^ (lc & 7)) << 3)];
        a1[ni] = __builtin_amdgcn_mfma_f32_16x16x32_bf16(qa[ks], kf, a1[ni], 0, 0, 0);
      }
#pragma unroll
    for (int r = 0; r < 4; ++r) {
      int trow = tq + lr * 4 + r;
      float sh = trow ? lcv[trow - 1] : 0.f;
#pragma unroll
      for (int ni = 0; ni < 4; ++ni) {
        int scol = ni * 16 + lc;
        float pv = (scol < trow) ? a1[ni][r] * __expf(sh - lcv[scol]) : 0.f;
        ps[trow * 64 + (((scol >> 3) ^ (trow & 7)) << 3) + (scol & 7)] = f2b(pv);
      }
    }
  } else {
    // GEMM2: past = (q . Sc^T) * exp(sh_t)
#pragma unroll
    for (int ni = 0; ni < 4; ++ni)
#pragma unroll
      for (int ks = 0; ks < 2; ++ks) {
        bf16x8 sf = *(const bf16x8*)&ss[(ni * 16 + lc) * 64 + (((ks * 4 + lr) ^ (lc & 7)) << 3)];
        a2[ni] = __builtin_amdgcn_mfma_f32_16x16x32_bf16(qa[ks], sf, a2[ni], 0, 0, 0);
      }
#pragma unroll
    for (int r = 0; r < 4; ++r) {
      int trow = tq + lr * 4 + r;
      float esh = __expf(trow ? lcv[trow - 1] : 0.f);
#pragma unroll
      for (int ni = 0; ni < 4; ++ni) a2[ni][r] *= esh;
    }
  }
  __syncthreads();
  if (wv >= 4) {
    // GEMM3: ret = past + P @ avT; write ret (bf16) into ks_ as out-GEMM A tile
    bf16x8 pa[2];
#pragma unroll
    for (int ks = 0; ks < 2; ++ks)
      pa[ks] = *(const bf16x8*)&ps[(tq + lc) * 64 + (((ks * 4 + lr) ^ (lc & 7)) << 3)];
#pragma unroll
    for (int ni = 0; ni < 4; ++ni)
#pragma unroll
      for (int ks = 0; ks < 2; ++ks) {
        bf16x8 vf = *(const bf16x8*)&vs[(ni * 16 + lc) * 64 + (((ks * 4 + lr) ^ (lc & 7)) << 3)];
        a2[ni] = __builtin_amdgcn_mfma_f32_16x16x32_bf16(pa[ks], vf, a2[ni], 0, 0, 0);
      }
#pragma unroll
    for (int r = 0; r < 4; ++r) {
      int trow = tq + lr * 4 + r;
#pragma unroll
      for (int ni = 0; ni < 4; ++ni) {
        int scol = ni * 16 + lc;
        ks_[trow * 64 + (((scol >> 3) ^ (trow & 7)) << 3) + (scol & 7)] = f2b(a2[ni][r]);
      }
    }
  }
  __syncthreads();

  // ---------- out-GEMM: M=64 x N=512 (this half) x K=64, 8 waves
  bf16x8 afr[4][2];
#pragma unroll
  for (int mi = 0; mi < 4; ++mi)
#pragma unroll
    for (int ks = 0; ks < 2; ++ks)
      afr[mi][ks] = *(const bf16x8*)&ks_[(mi * 16 + lc) * 64 + (((ks * 4 + lr) ^ (lc & 7)) << 3)];

#pragma unroll
  for (int g = 0; g < 2; ++g) {
    f32x4 acc[4][2];
#pragma unroll
    for (int mi = 0; mi < 4; ++mi)
#pragma unroll
      for (int ni = 0; ni < 2; ++ni) acc[mi][ni] = (f32x4){0.f, 0.f, 0.f, 0.f};
#pragma unroll
    for (int ks = 0; ks < 2; ++ks)
#pragma unroll
      for (int mi = 0; mi < 4; ++mi)
#pragma unroll
        for (int ni = 0; ni < 2; ++ni)
          acc[mi][ni] = __builtin_amdgcn_mfma_f32_16x16x32_bf16(afr[mi][ks], bw[g][ni * 2 + ks], acc[mi][ni], 0, 0, 0);
    float bo[2];
#pragma unroll
    for (int ni = 0; ni < 2; ++ni) bo[ni] = bout[colw + g * 256 + ni * 16 + lc];
#pragma unroll
    for (int mi = 0; mi < 4; ++mi)
#pragma unroll
      for (int r = 0; r < 4; ++r) {
        int grow = rbase + mi * 16 + lr * 4 + r;
#pragma unroll
        for (int ni = 0; ni < 2; ++ni)
          out[(size_t)grow * D + colw + g * 256 + ni * 16 + lc] = acc[mi][ni][r] + bo[ni];
      }
  }
}

extern "C" void kernel_launch(void* const* d_in, const int* in_sizes, int n_in,
                              void* d_out, int out_size, void* d_ws, size_t ws_size,
                              hipStream_t stream) {
  (void)in_sizes; (void)n_in; (void)out_size; (void)ws_size;
  const float* x     = (const float*)d_in[0];
  const float* state = (const float*)d_in[1];
  const float* Wk    = (const float*)d_in[2];
  const float* Wv    = (const float*)d_in[3];
  const float* Wq    = (const float*)d_in[4];
  const float* Wout  = (const float*)d_in[5];
  const float* bout  = (const float*)d_in[6];
  const float* Wg    = (const float*)d_in[7];
  const float* bg    = (const float*)d_in[8];
  const float* cosT  = (const float*)d_in[9];
  const float* sinT  = (const float*)d_in[10];

  float* out = (float*)d_out;
  float* newstate = out + (size_t)B * T * D;

  const int NTOK = B * T;            // 8192
  const int NE = B * T * S;          // 524288
  ushort* Wo   = (ushort*)d_ws;      // D*S = 65536
  ushort* qrb  = Wo + 65536;
  ushort* krb  = qrb + NE;
  ushort* avb  = krb + NE;
  ushort* avT  = avb + NE;
  ushort* Scb  = avT + NE;           // B*NC*4096 = NE
  float* knw   = (float*)(Scb + NE);
  float* alw   = knw + NTOK;
  float* lcum  = alw + NTOK;
  float* csum  = lcum + NTOK;        // B*NC
  float* Mc    = csum + B * NC;      // NE floats

  hipLaunchKernelGGL(k_proj, dim3(NTOK / 32 * 2), dim3(256), 0, stream, x, Wk, Wq, Wv, Wg, cosT, sinT, bg, qrb, krb, avb, knw, alw);
  hipLaunchKernelGGL(k_chunk, dim3(B * NC * 2), dim3(256), 0, stream, krb, avb, knw, alw, Wout, Wo, lcum, csum, Mc, avT);
  hipLaunchKernelGGL(k_scan, dim3(B * S * S / 64), dim3(64), 0, stream, state, csum, Mc, Scb, newstate);
  hipLaunchKernelGGL(k_ao, dim3(B * NC * 2), dim3(512), 0, stream, qrb, krb, avT, Scb, lcum, Wo, bout, out);
}

// Round 17
// 47.700 us; speedup vs baseline: 1.1239x; 1.1239x over previous
//
#include <hip/hip_runtime.h>
#include <math.h>

#define B 4
#define T 2048
#define D 1024
#define S 64
#define NC 32      // chunks per batch
#define CH 64      // chunk length

typedef float f32x4 __attribute__((ext_vector_type(4)));
typedef short bf16x8 __attribute__((ext_vector_type(8)));

__device__ inline ushort f2b(float f) {   // fp32 -> bf16 RNE
  unsigned u = __float_as_uint(f);
  u += 0x7fff + ((u >> 16) & 1);
  return (ushort)(u >> 16);
}
__device__ inline float b2f(ushort h) { return __uint_as_float(((unsigned)h) << 16); }

__device__ inline void gll16(const ushort* g, ushort* l) {
  __builtin_amdgcn_global_load_lds((const __attribute__((address_space(1))) void*)g,
                                   (__attribute__((address_space(3))) void*)l, 16, 0, 0);
}

// ---------------- weights -> bf16 (x4 vectorized). Columns: k 0-63 | q 64-127 | v 128-191 | gate 192
__global__ __launch_bounds__(256) void k_prep(const float* __restrict__ Wk,
                                              const float* __restrict__ Wv,
                                              const float* __restrict__ Wq,
                                              const float* __restrict__ Wg,
                                              const float* __restrict__ Wout,
                                              ushort* __restrict__ Wt,
                                              ushort* __restrict__ Wo) {
  int i = (blockIdx.x * 256 + threadIdx.x) * 4;     // 320 blocks cover 327680 elems
  union { ushort h[4]; uint2 v; } u;
  if (i < 256 * 1024) {
    int c = i >> 10, kk = i & 1023;
    float4 v4 = make_float4(0.f, 0.f, 0.f, 0.f);
    if (c < 64)        v4 = *(const float4*)&Wk[c * D + kk];
    else if (c < 128)  v4 = *(const float4*)&Wq[(c - 64) * D + kk];
    else if (c < 192)  v4 = *(const float4*)&Wv[(c - 128) * D + kk];
    else if (c == 192) v4 = *(const float4*)&Wg[kk];
    u.h[0] = f2b(v4.x); u.h[1] = f2b(v4.y); u.h[2] = f2b(v4.z); u.h[3] = f2b(v4.w);
    *(uint2*)&Wt[i] = u.v;
  } else {
    int j = i - 256 * 1024;
    if (j < D * S) {
      float4 v4 = *(const float4*)&Wout[j];
      u.h[0] = f2b(v4.x); u.h[1] = f2b(v4.y); u.h[2] = f2b(v4.z); u.h[3] = f2b(v4.w);
      *(uint2*)&Wo[j] = u.v;
    }
  }
}

// ---------------- bf16-MFMA projection, BM=32 BN=128 BK=128, grid 512 (2 blocks/CU)
// XCD-paired: (mt,cb=0)/(mt,cb=1) share the x tile via one XCD's L2.
__global__ __launch_bounds__(256) void k_proj(const float* __restrict__ x,
                                              const ushort* __restrict__ Wt,
                                              const float* __restrict__ cosT,
                                              const float* __restrict__ sinT,
                                              const float* __restrict__ bgp,
                                              ushort* __restrict__ qrb,
                                              ushort* __restrict__ krb,
                                              ushort* __restrict__ avb,
                                              float* __restrict__ knw,
                                              float* __restrict__ alw) {
  __shared__ ushort lA[2][32 * 128];    // 8KB x2
  __shared__ ushort lB[2][128 * 128];   // 32KB x2   (total 80KB -> 2 blocks/CU)
  int tid = threadIdx.x;
  int bid = blockIdx.x;
  int mt = (bid >> 4) * 8 + (bid & 7), cb = (bid >> 3) & 1;
  int row0 = mt * 32, col0 = cb * 128;
  int wv = tid >> 6, l = tid & 63, lr = l >> 4, lc = l & 15;
  int arow = tid >> 4, ac16 = tid & 15;
  int asw = (ac16 ^ (arow & 7)) << 3;
  const float* xr0 = &x[(size_t)(row0 + arow) * D + asw];
  const float* xr1 = &x[(size_t)(row0 + arow + 16) * D + asw];   // (arow+16)&7 == arow&7
  int gr4 = l >> 4, gc16 = l & 15;
  int f0 = ((wv >> 1) << 2) | (wv & 1);   // wave's first n-frag; RoPE pair is f0+2

  f32x4 acc[2][2];
#pragma unroll
  for (int mi = 0; mi < 2; ++mi)
#pragma unroll
    for (int ni = 0; ni < 2; ++ni) acc[mi][ni] = (f32x4){0.f, 0.f, 0.f, 0.f};

  float af0[8], af1[8];
  // ---- prologue: tile 0 -> buf 0
  {
    *(float4*)&af0[0] = *(const float4*)&xr0[0];
    *(float4*)&af0[4] = *(const float4*)&xr0[4];
    *(float4*)&af1[0] = *(const float4*)&xr1[0];
    *(float4*)&af1[4] = *(const float4*)&xr1[4];
#pragma unroll
    for (int j = 0; j < 8; ++j) {
      int rloc = wv * 32 + j * 4 + gr4;
      gll16(&Wt[(size_t)(col0 + rloc) * D + ((gc16 ^ (rloc & 7)) << 3)],
            (ushort*)&lB[0][(wv * 32 + j * 4) * 128]);
    }
    union { ushort h[8]; uint4 v; } u0, u1;
#pragma unroll
    for (int j = 0; j < 8; ++j) { u0.h[j] = f2b(af0[j]); u1.h[j] = f2b(af1[j]); }
    *(uint4*)&lA[0][arow * 128 + ac16 * 8] = u0.v;
    *(uint4*)&lA[0][(arow + 16) * 128 + ac16 * 8] = u1.v;
  }
  __syncthreads();

  const int NT = D / 128;
  for (int t = 0; t < NT; ++t) {
    int p = t & 1;
    if (t + 1 < NT) {
      int kc = (t + 1) * 128;
      *(float4*)&af0[0] = *(const float4*)&xr0[kc];
      *(float4*)&af0[4] = *(const float4*)&xr0[kc + 4];
      *(float4*)&af1[0] = *(const float4*)&xr1[kc];
      *(float4*)&af1[4] = *(const float4*)&xr1[kc + 4];
#pragma unroll
      for (int j = 0; j < 8; ++j) {
        int rloc = wv * 32 + j * 4 + gr4;
        gll16(&Wt[(size_t)(col0 + rloc) * D + kc + ((gc16 ^ (rloc & 7)) << 3)],
              (ushort*)&lB[p ^ 1][(wv * 32 + j * 4) * 128]);
      }
    }
    bf16x8 afr[2][4], bfr[2][4];
#pragma unroll
    for (int mi = 0; mi < 2; ++mi)
#pragma unroll
      for (int ks = 0; ks < 4; ++ks)
        afr[mi][ks] = *(const bf16x8*)&lA[p][(mi * 16 + lc) * 128 + (((ks * 4 + lr) ^ (lc & 7)) << 3)];
#pragma unroll
    for (int ni = 0; ni < 2; ++ni)
#pragma unroll
      for (int ks = 0; ks < 4; ++ks)
        bfr[ni][ks] = *(const bf16x8*)&lB[p][((f0 + 2 * ni) * 16 + lc) * 128 + (((ks * 4 + lr) ^ (lc & 7)) << 3)];
#pragma unroll
    for (int ks = 0; ks < 4; ++ks)
#pragma unroll
      for (int mi = 0; mi < 2; ++mi)
#pragma unroll
        for (int ni = 0; ni < 2; ++ni)
          acc[mi][ni] = __builtin_amdgcn_mfma_f32_16x16x32_bf16(afr[mi][ks], bfr[ni][ks], acc[mi][ni], 0, 0, 0);
    if (t + 1 < NT) {
      union { ushort h[8]; uint4 v; } u0, u1;
#pragma unroll
      for (int j = 0; j < 8; ++j) { u0.h[j] = f2b(af0[j]); u1.h[j] = f2b(af1[j]); }
      *(uint4*)&lA[p ^ 1][arow * 128 + ac16 * 8] = u0.v;
      *(uint4*)&lA[p ^ 1][(arow + 16) * 128 + ac16 * 8] = u1.v;
    }
    __syncthreads();
  }

  // epilogue. C/D map: row = mi*16+lr*4+r, col(frag f) = f*16+lc.
  float (*s_red)[32] = (float (*)[32])(&lA[0][0]);   // alias dead lA (keeps LDS at 80KB)
  float bgv = bgp[0];
  int c0 = (wv & 1) * 16 + lc;   // col within the 64-wide group; partner c0+32
  if (cb == 0) {
    ushort* dst = (wv < 2) ? krb : qrb;
#pragma unroll
    for (int mi = 0; mi < 2; ++mi)
#pragma unroll
      for (int r = 0; r < 4; ++r) {
        int lrow = mi * 16 + lr * 4 + r;
        int grow = row0 + lrow;
        int tt = grow & (T - 1);
        float a0 = acc[mi][0][r], a1 = acc[mi][1][r];
        float cv0 = cosT[tt * S + c0], sv0 = sinT[tt * S + c0];
        float cv1 = cosT[tt * S + c0 + 32], sv1 = sinT[tt * S + c0 + 32];
        float o0 = a0 * cv0 - a1 * sv0;
        float o1 = a1 * cv1 + a0 * sv1;
        dst[(size_t)grow * S + c0] = f2b(o0);
        dst[(size_t)grow * S + c0 + 32] = f2b(o1);
        if (wv < 2) {
          float nrm = o0 * o0 + o1 * o1;
#pragma unroll
          for (int off = 1; off < 16; off <<= 1) nrm += __shfl_xor(nrm, off, 64);
          if (lc == 0) s_red[wv][lrow] = nrm;
        }
      }
    __syncthreads();
    if (tid < 32) knw[row0 + tid] = s_red[0][tid] + s_red[1][tid];
  } else {
    if (wv == 2 && lc == 0) {    // gate = local col 64 = frag 4, lc==0
#pragma unroll
      for (int mi = 0; mi < 2; ++mi)
#pragma unroll
        for (int r = 0; r < 4; ++r) {
          int lrow = mi * 16 + lr * 4 + r;
          s_red[0][lrow] = 1.f / (1.f + __expf(-(acc[mi][0][r] + bgv)));
        }
    }
    __syncthreads();
    if (wv < 2) {
#pragma unroll
      for (int mi = 0; mi < 2; ++mi)
#pragma unroll
        for (int r = 0; r < 4; ++r) {
          int lrow = mi * 16 + lr * 4 + r, grow = row0 + lrow;
          float al = s_red[0][lrow];
          avb[(size_t)grow * S + c0] = f2b(al * acc[mi][0][r]);
          avb[(size_t)grow * S + c0 + 32] = f2b(al * acc[mi][1][r]);
        }
    }
    if (tid < 32) alw[row0 + tid] = s_red[0][tid];
  }
}

// ---------------- per-chunk: gate+cumsum + outer-product Mc + avT; 2 blocks/chunk (XCD-paired)
__global__ __launch_bounds__(256) void k_chunk(const ushort* __restrict__ krb,
                                               const ushort* __restrict__ avb,
                                               const float* __restrict__ knw,
                                               const float* __restrict__ alw,
                                               float* __restrict__ lcum,
                                               float* __restrict__ csum,
                                               float* __restrict__ Mc,
                                               ushort* __restrict__ avT) {
  int bid = blockIdx.x;
  int cid = (bid >> 4) * 8 + (bid & 7), half = (bid >> 3) & 1;
  int b = cid >> 5, ch = cid & 31;
  int rbase = b * T + ch * CH;
  __shared__ float lc[CH], wts[CH];
  __shared__ float krs[CH][68], avs[CH][68];
  int tid = threadIdx.x;

  if (tid < 64) {
    float al = alw[rbase + tid], kn = knw[rbase + tid];
    float gate = al * kn * 0.1f;
    float sp = (gate > 20.f) ? gate : log1pf(expf(gate));
    float g = expf(-sp);
    float v = logf(g + 1e-8f);
#pragma unroll
    for (int off = 1; off < 64; off <<= 1) {
      float n = __shfl_up(v, off, 64);
      if (tid >= off) v += n;
    }
    lc[tid] = v;
    if (half == 0) lcum[rbase + tid] = v;
  }
  for (int i = tid; i < 512; i += 256) {
    int t = i >> 3, c8 = i & 7;
    uint4 kv = *(const uint4*)&krb[(size_t)(rbase + t) * S + c8 * 8];
    uint4 a4 = *(const uint4*)&avb[(size_t)(rbase + t) * S + c8 * 8];
    const ushort* kh = (const ushort*)&kv;
    const ushort* ah = (const ushort*)&a4;
    float kf[8], af_[8];
#pragma unroll
    for (int j = 0; j < 8; ++j) { kf[j] = b2f(kh[j]); af_[j] = b2f(ah[j]); }
    *(float4*)&krs[t][c8 * 8]     = *(const float4*)&kf[0];
    *(float4*)&krs[t][c8 * 8 + 4] = *(const float4*)&kf[4];
    *(float4*)&avs[t][c8 * 8]     = *(const float4*)&af_[0];
    *(float4*)&avs[t][c8 * 8 + 4] = *(const float4*)&af_[4];
  }
  __syncthreads();
  float tot = lc[63];
  if (tid < 64) wts[tid] = __expf(tot - lc[tid]);   // exponent <= 0
  if (tid == 63 && half == 0) csum[b * NC + ch] = tot;
  __syncthreads();
  for (int i = tid; i < 2048; i += 256) {           // this half's v-range transpose
    int v = half * 32 + (i >> 6), t = i & 63;
    avT[(size_t)(b * NC + ch) * 4096 + v * 64 + t] = f2b(avs[t][v]);
  }
  int k = tid & 63, vg = tid >> 6;
  int v0 = half * 32 + vg * 8;
  float acc[8];
#pragma unroll
  for (int j = 0; j < 8; ++j) acc[j] = 0.f;
  for (int t = 0; t < CH; ++t) {
    float kw = krs[t][k] * wts[t];
    float4 a0 = *(const float4*)&avs[t][v0];
    float4 a1 = *(const float4*)&avs[t][v0 + 4];
    acc[0] += kw * a0.x; acc[1] += kw * a0.y; acc[2] += kw * a0.z; acc[3] += kw * a0.w;
    acc[4] += kw * a1.x; acc[5] += kw * a1.y; acc[6] += kw * a1.z; acc[7] += kw * a1.w;
  }
  size_t ob = (size_t)(b * NC + ch) * 4096;
#pragma unroll
  for (int j = 0; j < 8; ++j) Mc[ob + (v0 + j) * 64 + k] = acc[j];
}

// ---------------- chunk-level scan: preloaded Mc; 256 blocks x 64 threads
__global__ __launch_bounds__(64) void k_scan(const float* __restrict__ state,
                                             const float* __restrict__ csum,
                                             const float* __restrict__ Mc,
                                             ushort* __restrict__ Scb,
                                             float* __restrict__ newstate) {
  int gid = blockIdx.x * 64 + threadIdx.x;   // B*S*S = 16384
  int b = gid >> 12, e = gid & 4095;
  __shared__ float eg[NC];
  if (threadIdx.x < NC) eg[threadIdx.x] = __expf(csum[b * NC + threadIdx.x]);
  float m[NC];
#pragma unroll
  for (int c = 0; c < NC; ++c) m[c] = Mc[(size_t)(b * NC + c) * 4096 + e];
  float s = state[gid];
  __syncthreads();
#pragma unroll
  for (int c = 0; c < NC; ++c) {
    Scb[(size_t)(b * NC + c) * 4096 + e] = f2b(s);
    s = s * eg[c] + m[c];
  }
  newstate[gid] = s;
}

// ---------------- fused intra-chunk attention + output GEMM, 512 threads (8 waves)
// Wave-specialized attn: waves 0-3 do GEMM1 (QK^T) + P-decay, CONCURRENTLY waves 4-7
// do GEMM2 (q.Sc^T) + esh; after one barrier waves 4-7 do GEMM3 + ret write.
__global__ __launch_bounds__(512) void k_ao(const ushort* __restrict__ qrb,
                                            const ushort* __restrict__ krb,
                                            const ushort* __restrict__ avT,
                                            const ushort* __restrict__ Scb,
                                            const float* __restrict__ lcum,
                                            const ushort* __restrict__ Wo,
                                            const float* __restrict__ bout,
                                            float* __restrict__ out) {
  int bid = blockIdx.x;
  int cid = (bid >> 4) * 8 + (bid & 7), nh = (bid >> 3) & 1;
  int b = cid >> 5, ch = cid & 31;
  int rbase = b * T + ch * CH;
  size_t cb2 = (size_t)(b * NC + ch) * 4096;
  __shared__ ushort qs[64 * 64], ks_[64 * 64], vs[64 * 64], ss[64 * 64], ps[64 * 64];
  __shared__ float lcv[CH];
  int tid = threadIdx.x;
  int wv = tid >> 6, l = tid & 63, lr = l >> 4, lc = l & 15;
  int colw = nh * 512 + wv * 32;

  // issue ALL Wout frags at entry (latency hides under staging + attn)
  bf16x8 bw[2][4];
#pragma unroll
  for (int g = 0; g < 2; ++g)
#pragma unroll
    for (int ni = 0; ni < 2; ++ni)
#pragma unroll
      for (int ks = 0; ks < 2; ++ks)
        bw[g][ni * 2 + ks] = *(const bf16x8*)&Wo[(size_t)(colw + g * 256 + ni * 16 + lc) * 64 + (ks * 4 + lr) * 8];

  if (tid < 64) lcv[tid] = lcum[rbase + tid];
  {
    int row = tid >> 3, c8 = tid & 7;      // 512 threads = 512 chunk-slots
    int sc = (c8 ^ (row & 7)) << 3;
    *(uint4*)&qs[row * 64 + c8 * 8]  = *(const uint4*)&qrb[(size_t)(rbase + row) * S + sc];
    *(uint4*)&ks_[row * 64 + c8 * 8] = *(const uint4*)&krb[(size_t)(rbase + row) * S + sc];
    *(uint4*)&vs[row * 64 + c8 * 8]  = *(const uint4*)&avT[cb2 + row * 64 + sc];
    *(uint4*)&ss[row * 64 + c8 * 8]  = *(const uint4*)&Scb[cb2 + row * 64 + sc];
  }
  __syncthreads();

  int tq = (wv & 3) * 16;
  bf16x8 qa[2];
#pragma unroll
  for (int ks = 0; ks < 2; ++ks)
    qa[ks] = *(const bf16x8*)&qs[(tq + lc) * 64 + (((ks * 4 + lr) ^ (lc & 7)) << 3)];

  f32x4 a2[4];
#pragma unroll
  for (int ni = 0; ni < 4; ++ni) a2[ni] = (f32x4){0, 0, 0, 0};

  if (wv < 4) {
    // GEMM1: QK^T -> P with causal decay -> ps (swizzled)
    f32x4 a1[4];
#pragma unroll
    for (int ni = 0; ni < 4; ++ni) a1[ni] = (f32x4){0, 0, 0, 0};
#pragma unroll
    for (int ni = 0; ni < 4; ++ni)
#pragma unroll
      for (int ks = 0; ks < 2; ++ks) {
        bf16x8 kf = *(const bf16x8*)&ks_[(ni * 16 + lc) * 64 + (((ks * 4 + lr) ^ (lc & 7)) << 3)];
        a1[ni] = __builtin_amdgcn_mfma_f32_16x16x32_bf16(qa[ks], kf, a1[ni], 0, 0, 0);
      }
#pragma unroll
    for (int r = 0; r < 4; ++r) {
      int trow = tq + lr * 4 + r;
      float sh = trow ? lcv[trow - 1] : 0.f;
#pragma unroll
      for (int ni = 0; ni < 4; ++ni) {
        int scol = ni * 16 + lc;
        float pv = (scol < trow) ? a1[ni][r] * __expf(sh - lcv[scol]) : 0.f;
        ps[trow * 64 + (((scol >> 3) ^ (trow & 7)) << 3) + (scol & 7)] = f2b(pv);
      }
    }
  } else {
    // GEMM2: past = (q . Sc^T) * exp(sh_t)
#pragma unroll
    for (int ni = 0; ni < 4; ++ni)
#pragma unroll
      for (int ks = 0; ks < 2; ++ks) {
        bf16x8 sf = *(const bf16x8*)&ss[(ni * 16 + lc) * 64 + (((ks * 4 + lr) ^ (lc & 7)) << 3)];
        a2[ni] = __builtin_amdgcn_mfma_f32_16x16x32_bf16(qa[ks], sf, a2[ni], 0, 0, 0);
      }
#pragma unroll
    for (int r = 0; r < 4; ++r) {
      int trow = tq + lr * 4 + r;
      float esh = __expf(trow ? lcv[trow - 1] : 0.f);
#pragma unroll
      for (int ni = 0; ni < 4; ++ni) a2[ni][r] *= esh;
    }
  }
  __syncthreads();
  if (wv >= 4) {
    // GEMM3: ret = past + P @ avT; write ret (bf16) into ks_ as out-GEMM A tile
    bf16x8 pa[2];
#pragma unroll
    for (int ks = 0; ks < 2; ++ks)
      pa[ks] = *(const bf16x8*)&ps[(tq + lc) * 64 + (((ks * 4 + lr) ^ (lc & 7)) << 3)];
#pragma unroll
    for (int ni = 0; ni < 4; ++ni)
#pragma unroll
      for (int ks = 0; ks < 2; ++ks) {
        bf16x8 vf = *(const bf16x8*)&vs[(ni * 16 + lc) * 64 + (((ks * 4 + lr) ^ (lc & 7)) << 3)];
        a2[ni] = __builtin_amdgcn_mfma_f32_16x16x32_bf16(pa[ks], vf, a2[ni], 0, 0, 0);
      }
#pragma unroll
    for (int r = 0; r < 4; ++r) {
      int trow = tq + lr * 4 + r;
#pragma unroll
      for (int ni = 0; ni < 4; ++ni) {
        int scol = ni * 16 + lc;
        ks_[trow * 64 + (((scol >> 3) ^ (trow & 7)) << 3) + (scol & 7)] = f2b(a2[ni][r]);
      }
    }
  }
  __syncthreads();

  // ---------- out-GEMM: M=64 x N=512 (this half) x K=64, 8 waves
  bf16x8 afr[4][2];
#pragma unroll
  for (int mi = 0; mi < 4; ++mi)
#pragma unroll
    for (int ks = 0; ks < 2; ++ks)
      afr[mi][ks] = *(const bf16x8*)&ks_[(mi * 16 + lc) * 64 + (((ks * 4 + lr) ^ (lc & 7)) << 3)];

#pragma unroll
  for (int g = 0; g < 2; ++g) {
    f32x4 acc[4][2];
#pragma unroll
    for (int mi = 0; mi < 4; ++mi)
#pragma unroll
      for (int ni = 0; ni < 2; ++ni) acc[mi][ni] = (f32x4){0.f, 0.f, 0.f, 0.f};
#pragma unroll
    for (int ks = 0; ks < 2; ++ks)
#pragma unroll
      for (int mi = 0; mi < 4; ++mi)
#pragma unroll
        for (int ni = 0; ni < 2; ++ni)
          acc[mi][ni] = __builtin_amdgcn_mfma_f32_16x16x32_bf16(afr[mi][ks], bw[g][ni * 2 + ks], acc[mi][ni], 0, 0, 0);
    float bo[2];
#pragma unroll
    for (int ni = 0; ni < 2; ++ni) bo[ni] = bout[colw + g * 256 + ni * 16 + lc];
#pragma unroll
    for (int mi = 0; mi < 4; ++mi)
#pragma unroll
      for (int r = 0; r < 4; ++r) {
        int grow = rbase + mi * 16 + lr * 4 + r;
#pragma unroll
        for (int ni = 0; ni < 2; ++ni)
          out[(size_t)grow * D + colw + g * 256 + ni * 16 + lc] = acc[mi][ni][r] + bo[ni];
      }
  }
}

extern "C" void kernel_launch(void* const* d_in, const int* in_sizes, int n_in,
                              void* d_out, int out_size, void* d_ws, size_t ws_size,
                              hipStream_t stream) {
  (void)in_sizes; (void)n_in; (void)out_size; (void)ws_size;
  const float* x     = (const float*)d_in[0];
  const float* state = (const float*)d_in[1];
  const float* Wk    = (const float*)d_in[2];
  const float* Wv    = (const float*)d_in[3];
  const float* Wq    = (const float*)d_in[4];
  const float* Wout  = (const float*)d_in[5];
  const float* bout  = (const float*)d_in[6];
  const float* Wg    = (const float*)d_in[7];
  const float* bg    = (const float*)d_in[8];
  const float* cosT  = (const float*)d_in[9];
  const float* sinT  = (const float*)d_in[10];

  float* out = (float*)d_out;
  float* newstate = out + (size_t)B * T * D;

  const int NTOK = B * T;            // 8192
  const int NE = B * T * S;          // 524288
  ushort* Wt   = (ushort*)d_ws;      // 262144
  ushort* Wo   = Wt + 262144;        // 65536
  ushort* qrb  = Wo + 65536;
  ushort* krb  = qrb + NE;
  ushort* avb  = krb + NE;
  ushort* avT  = avb + NE;
  ushort* Scb  = avT + NE;           // B*NC*4096 = NE
  float* knw   = (float*)(Scb + NE);
  float* alw   = knw + NTOK;
  float* lcum  = alw + NTOK;
  float* csum  = lcum + NTOK;        // B*NC
  float* Mc    = csum + B * NC;      // NE floats

  hipLaunchKernelGGL(k_prep, dim3(320), dim3(256), 0, stream, Wk, Wv, Wq, Wg, Wout, Wt, Wo);
  hipLaunchKernelGGL(k_proj, dim3(NTOK / 32 * 2), dim3(256), 0, stream, x, Wt, cosT, sinT, bg, qrb, krb, avb, knw, alw);
  hipLaunchKernelGGL(k_chunk, dim3(B * NC * 2), dim3(256), 0, stream, krb, avb, knw, alw, lcum, csum, Mc, avT);
  hipLaunchKernelGGL(k_scan, dim3(B * S * S / 64), dim3(64), 0, stream, state, csum, Mc, Scb, newstate);
  hipLaunchKernelGGL(k_ao, dim3(B * NC * 2), dim3(512), 0, stream, qrb, krb, avT, Scb, lcum, Wo, bout, out);
}